// Round 2
// baseline (13750.769 us; speedup 1.0000x reference)
//
#include <hip/hip_runtime.h>
#include <math.h>

// GCN forward: 4 × [res = x@Wr+br ; x = relu(GCNConv(x) + res)] ; out = x@Wo+bo
// GCNConv(x) = sum_in-edges norm*h[src] + dinv^2*h[self] + bc,  h = x@Wc,
// norm[e] = dinv[row]*ew*dinv[col], deg = 1 + weighted in-degree (self-loop).
//
// Round 2: same fp32 baseline, but workspace capped at ~225 MiB (round-1 abort
// was most likely a d_ws overflow at 385 MB). Layer outputs ping-pong through
// an exactly-planned arena; h/res are computed in 512-column chunks so the
// chunk buffers are 16 MB each regardless of layer width.
//
// Arena plan (float offsets, M1 = 2^20):
//   L0: out@[0,8M)    chunks@[8M,16M)    (cur = x input)
//   L1: out@[8M,24M)  chunks@[24M,32M)   (cur = [0,8M))
//   L2: out@[24M,56M) chunks@[0,8M)      (cur = [8M,24M))
//   L3: out@[0,16M)   chunks@[16M,24M)   (cur = [24M,56M))
//   Lo: reads [0,16M) -> d_out
//   CSR @ 56M (~0.7 MB)   => peak ~56.2M floats = 225 MiB

#define NN 8192
#define NE 65536
#define CW 512
#define M1 (1u << 20)

// ---------------------------------------------------------------- small kernels
__global__ void k_init_deg(float* __restrict__ deg) {
    int i = blockIdx.x * 256 + threadIdx.x;
    if (i < NN) deg[i] = 1.0f;               // self-loop weight
}
__global__ void k_zero_cnt(int* __restrict__ cnt) {
    int i = blockIdx.x * 256 + threadIdx.x;
    if (i < NN) cnt[i] = 0;
}
__global__ void k_deg_edges(const int* __restrict__ col, const float* __restrict__ ew,
                            float* __restrict__ deg) {
    int e = blockIdx.x * 256 + threadIdx.x;
    if (e < NE) atomicAdd(&deg[col[e]], ew[e]);
}
__global__ void k_cnt_edges(const int* __restrict__ col, int* __restrict__ cnt) {
    int e = blockIdx.x * 256 + threadIdx.x;
    if (e < NE) atomicAdd(&cnt[col[e]], 1);
}
__global__ void k_dinv(const float* __restrict__ deg, float* __restrict__ dinv) {
    int i = blockIdx.x * 256 + threadIdx.x;
    if (i < NN) { float d = deg[i]; dinv[i] = d > 0.f ? rsqrtf(d) : 0.f; }
}
// exclusive prefix sum over NN=8192 counts, single block of 1024 threads x 8 each
__global__ __launch_bounds__(1024) void k_scan(const int* __restrict__ cnt,
                                               int* __restrict__ colptr,
                                               int* __restrict__ fillpos) {
    __shared__ int part[1024];
    int tid = threadIdx.x;
    int local[8];
    int s = 0;
#pragma unroll
    for (int i = 0; i < 8; ++i) { local[i] = cnt[tid * 8 + i]; s += local[i]; }
    part[tid] = s;
    __syncthreads();
    for (int off = 1; off < 1024; off <<= 1) {
        int add = (tid >= off) ? part[tid - off] : 0;
        __syncthreads();
        part[tid] += add;
        __syncthreads();
    }
    int run = (tid == 0) ? 0 : part[tid - 1];
#pragma unroll
    for (int i = 0; i < 8; ++i) {
        colptr[tid * 8 + i] = run;
        fillpos[tid * 8 + i] = run;
        run += local[i];
    }
    if (tid == 1023) colptr[NN] = run;       // == NE
}
__global__ void k_fill(const int* __restrict__ row, const int* __restrict__ col,
                       const float* __restrict__ ew, const float* __restrict__ dinv,
                       int* __restrict__ fillpos, int* __restrict__ csr_src,
                       float* __restrict__ csr_w) {
    int e = blockIdx.x * 256 + threadIdx.x;
    if (e >= NE) return;
    int r = row[e], c = col[e];
    float nrm = dinv[r] * ew[e] * dinv[c];
    int p = atomicAdd(&fillpos[c], 1);
    csr_src[p] = r;
    csr_w[p] = nrm;
}

// ---------------------------------------------------------------- SGEMM fp32
// C[128-row blocks of 8192, N cols] = A @ B (+bias). K % 8 == 0.
// GUARD=false requires N % 128 == 0 (chunk panels). bias indexed by local col.
template <bool BIAS, bool GUARD>
__global__ __launch_bounds__(256) void sgemm(const float* __restrict__ A, int lda,
                                             const float* __restrict__ B, int ldb,
                                             const float* __restrict__ bias,
                                             float* __restrict__ C, int ldc,
                                             int N, int K) {
    __shared__ float As[8][128];   // transposed A tile: As[k][m]
    __shared__ float Bs[8][128];
    const int tid  = threadIdx.x;
    const int row0 = blockIdx.y * 128;
    const int col0 = blockIdx.x * 128;

    const int arow = tid >> 1;            // 0..127
    const int acol = (tid & 1) << 2;      // 0 or 4
    const int brow = tid >> 5;            // 0..7
    const int bcol = (tid & 31) << 2;     // 0..124

    const int trow = (tid >> 4) << 3;     // 0..120
    const int tcol = (tid & 15) << 3;     // 0..120

    float acc[8][8];
#pragma unroll
    for (int i = 0; i < 8; ++i)
#pragma unroll
        for (int j = 0; j < 8; ++j) acc[i][j] = 0.f;

    const float* Arow = A + (size_t)(row0 + arow) * lda + acol;

    for (int k0 = 0; k0 < K; k0 += 8) {
        float4 av = *(const float4*)(Arow + k0);
        float4 bv;
        const int gc = col0 + bcol;
        const float* bp = B + (size_t)(k0 + brow) * ldb + gc;
        if (!GUARD || gc + 3 < N) {
            bv = *(const float4*)bp;
        } else {
            bv.x = (gc + 0 < N) ? bp[0] : 0.f;
            bv.y = (gc + 1 < N) ? bp[1] : 0.f;
            bv.z = (gc + 2 < N) ? bp[2] : 0.f;
            bv.w = (gc + 3 < N) ? bp[3] : 0.f;
        }
        As[acol + 0][arow] = av.x;
        As[acol + 1][arow] = av.y;
        As[acol + 2][arow] = av.z;
        As[acol + 3][arow] = av.w;
        *(float4*)&Bs[brow][bcol] = bv;
        __syncthreads();
#pragma unroll
        for (int k = 0; k < 8; ++k) {
            float a[8], b[8];
            *(float4*)&a[0] = *(const float4*)&As[k][trow];
            *(float4*)&a[4] = *(const float4*)&As[k][trow + 4];
            *(float4*)&b[0] = *(const float4*)&Bs[k][tcol];
            *(float4*)&b[4] = *(const float4*)&Bs[k][tcol + 4];
#pragma unroll
            for (int i = 0; i < 8; ++i)
#pragma unroll
                for (int j = 0; j < 8; ++j)
                    acc[i][j] = fmaf(a[i], b[j], acc[i][j]);
        }
        __syncthreads();
    }

#pragma unroll
    for (int i = 0; i < 8; ++i) {
        const int gr = row0 + trow + i;
        float* cp = C + (size_t)gr * ldc + col0 + tcol;
#pragma unroll
        for (int jj = 0; jj < 2; ++jj) {
            const int j0 = jj * 4;
            const int gc = col0 + tcol + j0;
            float4 v;
            v.x = acc[i][j0 + 0]; v.y = acc[i][j0 + 1];
            v.z = acc[i][j0 + 2]; v.w = acc[i][j0 + 3];
            if (BIAS) {
                if (!GUARD || gc + 0 < N) v.x += bias[gc + 0];
                if (!GUARD || gc + 1 < N) v.y += bias[gc + 1];
                if (!GUARD || gc + 2 < N) v.z += bias[gc + 2];
                if (!GUARD || gc + 3 < N) v.w += bias[gc + 3];
            }
            if (!GUARD || gc + 3 < N) {
                *(float4*)(cp + j0) = v;
            } else {
                if (gc + 0 < N) cp[j0 + 0] = v.x;
                if (gc + 1 < N) cp[j0 + 1] = v.y;
                if (gc + 2 < N) cp[j0 + 2] = v.z;
                if (gc + 3 < N) cp[j0 + 3] = v.w;
            }
        }
    }
}

// ---------------------------------------- fused aggregate + bias + residual + relu
// For one 512-col chunk: out[i][c0+f] = relu( dinv[i]^2*h[i][f] + sum_e w*h[src][f]
//                                             + bc[c0+f] + res[i][f] )
// h/res are [NN][CW] chunk buffers; out is strided by ldout with c0 pre-applied.
__global__ __launch_bounds__(128) void k_fuse(const float* __restrict__ h,
                                              const float* __restrict__ res,
                                              const float* __restrict__ bcp,
                                              const float* __restrict__ dinv,
                                              const int* __restrict__ colptr,
                                              const int* __restrict__ csr_src,
                                              const float* __restrict__ csr_w,
                                              float* __restrict__ out, int ldout) {
    const int node = blockIdx.x;
    const int f = threadIdx.x << 2;                     // 0..508
    const float di = dinv[node];
    const float sn = di * di;
    const float4 hv = *(const float4*)(h + (size_t)node * CW + f);
    float4 s = make_float4(sn * hv.x, sn * hv.y, sn * hv.z, sn * hv.w);
    const int e1 = colptr[node + 1];
    for (int e = colptr[node]; e < e1; ++e) {
        const int src = csr_src[e];
        const float w = csr_w[e];
        const float4 v = *(const float4*)(h + (size_t)src * CW + f);
        s.x = fmaf(w, v.x, s.x);
        s.y = fmaf(w, v.y, s.y);
        s.z = fmaf(w, v.z, s.z);
        s.w = fmaf(w, v.w, s.w);
    }
    const float4 r = *(const float4*)(res + (size_t)node * CW + f);
    const float4 b = *(const float4*)(bcp + f);
    float4 o;
    o.x = fmaxf(s.x + b.x + r.x, 0.f);
    o.y = fmaxf(s.y + b.y + r.y, 0.f);
    o.z = fmaxf(s.z + b.z + r.z, 0.f);
    o.w = fmaxf(s.w + b.w + r.w, 0.f);
    *(float4*)(out + (size_t)node * ldout + f) = o;
}

// ---------------------------------------------------------------- launch
extern "C" void kernel_launch(void* const* d_in, const int* in_sizes, int n_in,
                              void* d_out, int out_size, void* d_ws, size_t ws_size,
                              hipStream_t stream) {
    const float* x  = (const float*)d_in[0];
    const int*   ei = (const int*)d_in[1];
    const float* ew = (const float*)d_in[2];
    const int* row = ei;
    const int* col = ei + NE;
    const float *Wc[4], *bc[4], *Wr[4], *br[4];
    for (int i = 0; i < 4; ++i) {
        Wc[i] = (const float*)d_in[3 + 4 * i];
        bc[i] = (const float*)d_in[4 + 4 * i];
        Wr[i] = (const float*)d_in[5 + 4 * i];
        br[i] = (const float*)d_in[6 + 4 * i];
    }
    const float* Wo = (const float*)d_in[19];
    const float* bo = (const float*)d_in[20];
    float* out = (float*)d_out;

    float* ws = (float*)d_ws;
    // CSR block at 56M floats
    float* deg   = ws + (size_t)56 * M1;
    float* dinv  = deg + NN;
    float* csr_w = dinv + NN;
    int* cnt     = (int*)(csr_w + NE);
    int* fillpos = cnt + NN;
    int* colptr  = fillpos + NN;        // NN+1 entries
    int* csr_src = colptr + NN + 8;

    // ---- preprocessing (every call: ws is re-poisoned by harness)
    k_init_deg<<<NN / 256, 256, 0, stream>>>(deg);
    k_zero_cnt<<<NN / 256, 256, 0, stream>>>(cnt);
    k_deg_edges<<<NE / 256, 256, 0, stream>>>(col, ew, deg);
    k_cnt_edges<<<NE / 256, 256, 0, stream>>>(col, cnt);
    k_dinv<<<NN / 256, 256, 0, stream>>>(deg, dinv);
    k_scan<<<1, 1024, 0, stream>>>(cnt, colptr, fillpos);
    k_fill<<<NE / 256, 256, 0, stream>>>(row, col, ew, dinv, fillpos, csr_src, csr_w);

    // ---- 4 GCN layers, 512-col chunked
    const int dims[5] = {512, 1024, 2048, 4096, 2048};
    const size_t outOff[4] = {0, (size_t)8 * M1, (size_t)24 * M1, 0};
    const size_t chkOff[4] = {(size_t)8 * M1, (size_t)24 * M1, 0, (size_t)16 * M1};

    const float* cur = x;
    for (int l = 0; l < 4; ++l) {
        const int K = dims[l], Nf = dims[l + 1];
        float* outb = ws + outOff[l];
        float* hb   = ws + chkOff[l];
        float* rb   = hb + (size_t)4 * M1;
        dim3 grid(CW / 128, NN / 128);
        for (int c0 = 0; c0 < Nf; c0 += CW) {
            sgemm<false, false><<<grid, 256, 0, stream>>>(cur, K, Wc[l] + c0, Nf,
                                                          nullptr, hb, CW, CW, K);
            sgemm<true, false><<<grid, 256, 0, stream>>>(cur, K, Wr[l] + c0, Nf,
                                                         br[l] + c0, rb, CW, CW, K);
            k_fuse<<<NN, 128, 0, stream>>>(hb, rb, bc[l] + c0, dinv, colptr,
                                           csr_src, csr_w, outb + c0, Nf);
        }
        cur = outb;
    }

    // ---- output projection [8192,2048] @ [2048,1000] + bo
    dim3 grid((1000 + 127) / 128, NN / 128);
    sgemm<true, true><<<grid, 256, 0, stream>>>(cur, 2048, Wo, 1000, bo, out, 1000,
                                                1000, 2048);
}

// Round 3
// 4363.307 us; speedup vs baseline: 3.1515x; 3.1515x over previous
//
#include <hip/hip_runtime.h>
#include <math.h>

// GCN forward: 4 × [res = x@Wr+br ; x = relu(GCNConv(x) + res)] ; out = x@Wo+bo
// Round 3: fp32 GEMMs -> split-bf16 MFMA emulation (hi+lo bf16, 3 MFMAs per
// product, fp32 accumulate). Activations/weights stored as bf16 hi/lo pairs
// (same bytes as fp32). GEMM: 128x128 tile, BK=32, global_load_lds(16B),
// XOR-swizzled LDS, mfma_f32_16x16x32_bf16. B panels pre-transposed per chunk.

#define NN 8192
#define NE 65536

typedef float f32x4 __attribute__((ext_vector_type(4)));
typedef __bf16 bf16x8 __attribute__((ext_vector_type(8)));
typedef unsigned short u16;

__device__ __forceinline__ u16 f2bf(float f) {          // RNE fp32 -> bf16 bits
    unsigned int u = __float_as_uint(f);
    u += 0x7FFFu + ((u >> 16) & 1u);
    return (u16)(u >> 16);
}
__device__ __forceinline__ float bf2f(u16 h) {
    return __uint_as_float(((unsigned int)h) << 16);
}

// ---------------------------------------------------------------- CSR kernels
__global__ void k_init_deg(float* __restrict__ deg) {
    int i = blockIdx.x * 256 + threadIdx.x;
    if (i < NN) deg[i] = 1.0f;
}
__global__ void k_zero_cnt(int* __restrict__ cnt) {
    int i = blockIdx.x * 256 + threadIdx.x;
    if (i < NN) cnt[i] = 0;
}
__global__ void k_deg_edges(const int* __restrict__ col, const float* __restrict__ ew,
                            float* __restrict__ deg) {
    int e = blockIdx.x * 256 + threadIdx.x;
    if (e < NE) atomicAdd(&deg[col[e]], ew[e]);
}
__global__ void k_cnt_edges(const int* __restrict__ col, int* __restrict__ cnt) {
    int e = blockIdx.x * 256 + threadIdx.x;
    if (e < NE) atomicAdd(&cnt[col[e]], 1);
}
__global__ void k_dinv(const float* __restrict__ deg, float* __restrict__ dinv) {
    int i = blockIdx.x * 256 + threadIdx.x;
    if (i < NN) { float d = deg[i]; dinv[i] = d > 0.f ? rsqrtf(d) : 0.f; }
}
__global__ __launch_bounds__(1024) void k_scan(const int* __restrict__ cnt,
                                               int* __restrict__ colptr,
                                               int* __restrict__ fillpos) {
    __shared__ int part[1024];
    int tid = threadIdx.x;
    int local[8];
    int s = 0;
#pragma unroll
    for (int i = 0; i < 8; ++i) { local[i] = cnt[tid * 8 + i]; s += local[i]; }
    part[tid] = s;
    __syncthreads();
    for (int off = 1; off < 1024; off <<= 1) {
        int add = (tid >= off) ? part[tid - off] : 0;
        __syncthreads();
        part[tid] += add;
        __syncthreads();
    }
    int run = (tid == 0) ? 0 : part[tid - 1];
#pragma unroll
    for (int i = 0; i < 8; ++i) {
        colptr[tid * 8 + i] = run;
        fillpos[tid * 8 + i] = run;
        run += local[i];
    }
    if (tid == 1023) colptr[NN] = run;
}
__global__ void k_fill(const int* __restrict__ row, const int* __restrict__ col,
                       const float* __restrict__ ew, const float* __restrict__ dinv,
                       int* __restrict__ fillpos, int* __restrict__ csr_src,
                       float* __restrict__ csr_w) {
    int e = blockIdx.x * 256 + threadIdx.x;
    if (e >= NE) return;
    int r = row[e], c = col[e];
    float nrm = dinv[r] * ew[e] * dinv[c];
    int p = atomicAdd(&fillpos[c], 1);
    csr_src[p] = r;
    csr_w[p] = nrm;
}

// ------------------------------------------------------------- split fp32->hi/lo
__global__ void k_split_x(const float* __restrict__ x, u16* __restrict__ hi,
                          u16* __restrict__ lo, int n) {
    int i = blockIdx.x * 256 + threadIdx.x;
    if (i >= n) return;
    float v = x[i];
    u16 h = f2bf(v);
    hi[i] = h;
    lo[i] = f2bf(v - bf2f(h));
}

// --------------------------------------- weight panel: transpose + split
// W [K, ldw] fp32 -> panel hi/lo [ncols][K] bf16 (K-contiguous), cols [c0, c0+32*gridY)
__global__ __launch_bounds__(256) void k_wpanel(const float* __restrict__ W, int ldw,
                                                int c0, int nvalid, int K,
                                                u16* __restrict__ phi,
                                                u16* __restrict__ plo) {
    __shared__ float t[32][33];
    const int k0 = blockIdx.x * 32;
    const int n0 = blockIdx.y * 32;
    const int tx = threadIdx.x, ty = threadIdx.y;     // (32, 8)
#pragma unroll
    for (int i = 0; i < 4; ++i) {
        int k = k0 + ty + i * 8;
        int n = c0 + n0 + tx;
        t[ty + i * 8][tx] = (n < nvalid) ? W[(size_t)k * ldw + n] : 0.f;
    }
    __syncthreads();
#pragma unroll
    for (int i = 0; i < 4; ++i) {
        int n = n0 + ty + i * 8;          // local panel row
        int k = k0 + tx;
        float v = t[tx][ty + i * 8];
        u16 h = f2bf(v);
        phi[(size_t)n * K + k] = h;
        plo[(size_t)n * K + k] = f2bf(v - bf2f(h));
    }
}

// ---------------------------------------------------- split-bf16 MFMA GEMM
// C[f32, 8192 x ncols] = A @ B^T-panel (+bias). A: hi/lo [NN][K]; B: hi/lo [ncols][K].
// 128x128 tile, BK=32, 4 waves (2x2), each wave 64x64 (4x4 frags of 16x16).
// LDS tiles [128 rows][32 k] bf16 with 16B-slot XOR swizzle: slot' = slot ^ ((row>>1)&3).
#define GLDS(g, l) __builtin_amdgcn_global_load_lds(                         \
    (const __attribute__((address_space(1))) void*)(g),                      \
    (__attribute__((address_space(3))) void*)(l), 16, 0, 0)

template <bool BIAS, bool GUARD>
__global__ __launch_bounds__(256) void mgemm(const u16* __restrict__ Ahi,
                                             const u16* __restrict__ Alo,
                                             const u16* __restrict__ Bhi,
                                             const u16* __restrict__ Blo,
                                             const float* __restrict__ bias,
                                             float* __restrict__ C,
                                             int K, int ldc, int Nvalid) {
    __shared__ __align__(16) u16 smem[16384];   // 4 tiles x 8KB: Ahi,Alo,Bhi,Blo
    char* sm = (char*)smem;
    const int tid  = threadIdx.x;
    const int lane = tid & 63;
    const int w    = tid >> 6;
    const int wr   = w >> 1, wc = w & 1;
    const int row0 = blockIdx.y * 128;
    const int col0 = blockIdx.x * 128;

    // staging: pass p covers LDS linear [ (p*4+w)*1024, +1024 ) bytes per wave
    size_t aoffg[2], boffg[2];
    unsigned ldsoff[2];
#pragma unroll
    for (int p = 0; p < 2; ++p) {
        int idx = ((p * 4 + w) << 6) + lane;          // 0..511 (16B units)
        int r = idx >> 2;
        int s = (idx & 3) ^ ((r >> 1) & 3);           // inverse swizzle on source
        aoffg[p] = (size_t)(row0 + r) * K + s * 8;
        boffg[p] = (size_t)(col0 + r) * K + s * 8;
        ldsoff[p] = (unsigned)((p * 4 + w) << 10);
    }

    // fragment LDS byte offsets (row*64 + swizzled 16B slot)
    const int swz = (((lane >> 4) ^ ((lane >> 1) & 3)) << 4);
    int aoff[4], boff[4];
#pragma unroll
    for (int m = 0; m < 4; ++m) {
        aoff[m] = (wr * 64 + m * 16 + (lane & 15)) * 64 + swz;
        boff[m] = (wc * 64 + m * 16 + (lane & 15)) * 64 + swz;
    }

    f32x4 acc[4][4];
#pragma unroll
    for (int m = 0; m < 4; ++m)
#pragma unroll
        for (int n = 0; n < 4; ++n) acc[m][n] = (f32x4){0.f, 0.f, 0.f, 0.f};

    for (int k0 = 0; k0 < K; k0 += 32) {
#pragma unroll
        for (int p = 0; p < 2; ++p) {
            GLDS(Ahi + aoffg[p] + k0, sm + 0     + ldsoff[p]);
            GLDS(Alo + aoffg[p] + k0, sm + 8192  + ldsoff[p]);
            GLDS(Bhi + boffg[p] + k0, sm + 16384 + ldsoff[p]);
            GLDS(Blo + boffg[p] + k0, sm + 24576 + ldsoff[p]);
        }
        __syncthreads();
        bf16x8 ah[4], al[4], bh[4], bl[4];
#pragma unroll
        for (int m = 0; m < 4; ++m) {
            ah[m] = *(const bf16x8*)(sm + 0     + aoff[m]);
            al[m] = *(const bf16x8*)(sm + 8192  + aoff[m]);
            bh[m] = *(const bf16x8*)(sm + 16384 + boff[m]);
            bl[m] = *(const bf16x8*)(sm + 24576 + boff[m]);
        }
#pragma unroll
        for (int m = 0; m < 4; ++m)
#pragma unroll
            for (int n = 0; n < 4; ++n) {
                acc[m][n] = __builtin_amdgcn_mfma_f32_16x16x32_bf16(ah[m], bh[n], acc[m][n], 0, 0, 0);
                acc[m][n] = __builtin_amdgcn_mfma_f32_16x16x32_bf16(al[m], bh[n], acc[m][n], 0, 0, 0);
                acc[m][n] = __builtin_amdgcn_mfma_f32_16x16x32_bf16(ah[m], bl[n], acc[m][n], 0, 0, 0);
            }
        __syncthreads();
    }

    // epilogue: C/D layout col = lane&15, row = (lane>>4)*4 + j  [verified]
#pragma unroll
    for (int m = 0; m < 4; ++m) {
        const int r = row0 + wr * 64 + m * 16 + ((lane >> 4) << 2);
#pragma unroll
        for (int n = 0; n < 4; ++n) {
            const int cl = col0 + wc * 64 + n * 16 + (lane & 15);
            if (GUARD && cl >= Nvalid) continue;
            const float b = BIAS ? bias[cl] : 0.f;
#pragma unroll
            for (int j = 0; j < 4; ++j)
                C[(size_t)(r + j) * ldc + cl] = acc[m][n][j] + b;
        }
    }
}

// ------------------------- fused aggregate + bias + residual + relu + split-write
__global__ __launch_bounds__(128) void k_fuse(const float* __restrict__ h,
                                              const float* __restrict__ res,
                                              const float* __restrict__ bcp,
                                              const float* __restrict__ dinv,
                                              const int* __restrict__ colptr,
                                              const int* __restrict__ csr_src,
                                              const float* __restrict__ csr_w,
                                              u16* __restrict__ ohi,
                                              u16* __restrict__ olo,
                                              int ldout, int cw) {
    const int node = blockIdx.x;
    const int f = (blockIdx.y * 128 + threadIdx.x) << 2;
    const float di = dinv[node];
    const float sn = di * di;
    const float4 hv = *(const float4*)(h + (size_t)node * cw + f);
    float4 s = make_float4(sn * hv.x, sn * hv.y, sn * hv.z, sn * hv.w);
    const int e1 = colptr[node + 1];
    for (int e = colptr[node]; e < e1; ++e) {
        const int src = csr_src[e];
        const float wgt = csr_w[e];
        const float4 v = *(const float4*)(h + (size_t)src * cw + f);
        s.x = fmaf(wgt, v.x, s.x);
        s.y = fmaf(wgt, v.y, s.y);
        s.z = fmaf(wgt, v.z, s.z);
        s.w = fmaf(wgt, v.w, s.w);
    }
    const float4 r = *(const float4*)(res + (size_t)node * cw + f);
    const float4 b = *(const float4*)(bcp + f);
    float o0 = fmaxf(s.x + b.x + r.x, 0.f);
    float o1 = fmaxf(s.y + b.y + r.y, 0.f);
    float o2 = fmaxf(s.z + b.z + r.z, 0.f);
    float o3 = fmaxf(s.w + b.w + r.w, 0.f);
    ushort4 vh, vl;
    vh.x = f2bf(o0); vl.x = f2bf(o0 - bf2f(vh.x));
    vh.y = f2bf(o1); vl.y = f2bf(o1 - bf2f(vh.y));
    vh.z = f2bf(o2); vl.z = f2bf(o2 - bf2f(vh.z));
    vh.w = f2bf(o3); vl.w = f2bf(o3 - bf2f(vh.w));
    const size_t oidx = (size_t)node * ldout + f;
    *(ushort4*)(ohi + oidx) = vh;
    *(ushort4*)(olo + oidx) = vl;
}

// ---------------------------------------------------------------- launch
extern "C" void kernel_launch(void* const* d_in, const int* in_sizes, int n_in,
                              void* d_out, int out_size, void* d_ws, size_t ws_size,
                              hipStream_t stream) {
    const float* x  = (const float*)d_in[0];
    const int*   ei = (const int*)d_in[1];
    const float* ew = (const float*)d_in[2];
    const int* row = ei;
    const int* col = ei + NE;
    const float *Wc[4], *bc[4], *Wr[4], *br[4];
    for (int i = 0; i < 4; ++i) {
        Wc[i] = (const float*)d_in[3 + 4 * i];
        bc[i] = (const float*)d_in[4 + 4 * i];
        Wr[i] = (const float*)d_in[5 + 4 * i];
        br[i] = (const float*)d_in[6 + 4 * i];
    }
    const float* Wo = (const float*)d_in[19];
    const float* bo = (const float*)d_in[20];

    // ---- adaptive arena (ws_size >= 225 MB known-safe; >= 270 MB enables CW=1024)
    const bool big = ws_size >= 270500000ull;
    const int CW = big ? 1024 : 512;

    char* wsb = (char*)d_ws;
    u16* regA_hi = (u16*)wsb;                                  // A pair: up to 2048 wide
    u16* regA_lo = regA_hi + (size_t)NN * 2048;
    u16* regB_hi = (u16*)(wsb + (size_t)NN * 2048 * 4);        // B pair: up to 4096 wide
    u16* regB_lo = regB_hi + (size_t)NN * 4096;
    char* hRegion = wsb + (size_t)NN * 2048 * 4 + (size_t)NN * 4096 * 4;  // 201.3 MB
    float* hChunk = (float*)hRegion;
    float* resChunk = big ? (float*)(hRegion + (size_t)NN * 1024 * 4) : (float*)d_out;
    char* csrBase = hRegion + (big ? (size_t)NN * 1024 * 8 : (size_t)NN * 512 * 4);
    // layer weight panel scratch lives in d_out (overwritten by final projection)
    u16* panel = big ? (u16*)d_out : (u16*)((char*)d_out + (size_t)NN * 512 * 4);

    float* deg   = (float*)csrBase;
    float* dinv  = deg + NN;
    float* csr_w = dinv + NN;
    int* cnt     = (int*)(csr_w + NE);
    int* fillpos = cnt + NN;
    int* colptr  = fillpos + NN;
    int* csr_src = colptr + NN + 8;

    // ---- preprocessing
    k_init_deg<<<NN / 256, 256, 0, stream>>>(deg);
    k_zero_cnt<<<NN / 256, 256, 0, stream>>>(cnt);
    k_deg_edges<<<NE / 256, 256, 0, stream>>>(col, ew, deg);
    k_cnt_edges<<<NE / 256, 256, 0, stream>>>(col, cnt);
    k_dinv<<<NN / 256, 256, 0, stream>>>(deg, dinv);
    k_scan<<<1, 1024, 0, stream>>>(cnt, colptr, fillpos);
    k_fill<<<NE / 256, 256, 0, stream>>>(row, col, ew, dinv, fillpos, csr_src, csr_w);

    // ---- split input x0 -> region A
    k_split_x<<<(NN * 512) / 256, 256, 0, stream>>>(x, regA_hi, regA_lo, NN * 512);

    // ---- 4 GCN layers (even layers read A write B; odd read B write A)
    const int dims[5] = {512, 1024, 2048, 4096, 2048};
    for (int l = 0; l < 4; ++l) {
        const int K = dims[l], Nf = dims[l + 1];
        const u16 *curHi, *curLo;
        u16 *nxtHi, *nxtLo;
        if ((l & 1) == 0) { curHi = regA_hi; curLo = regA_lo; nxtHi = regB_hi; nxtLo = regB_lo; }
        else              { curHi = regB_hi; curLo = regB_lo; nxtHi = regA_hi; nxtLo = regA_lo; }
        u16* panel_lo = panel + (size_t)CW * K;
        dim3 wgrid(K / 32, CW / 32);
        dim3 ggrid(CW / 128, NN / 128);
        dim3 fgrid(NN, CW / 512);
        for (int c0 = 0; c0 < Nf; c0 += CW) {
            k_wpanel<<<wgrid, dim3(32, 8), 0, stream>>>(Wr[l], Nf, c0, Nf, K, panel, panel_lo);
            mgemm<true, false><<<ggrid, 256, 0, stream>>>(curHi, curLo, panel, panel_lo,
                                                          br[l] + c0, resChunk, K, CW, CW);
            k_wpanel<<<wgrid, dim3(32, 8), 0, stream>>>(Wc[l], Nf, c0, Nf, K, panel, panel_lo);
            mgemm<false, false><<<ggrid, 256, 0, stream>>>(curHi, curLo, panel, panel_lo,
                                                           nullptr, hChunk, K, CW, CW);
            k_fuse<<<fgrid, 128, 0, stream>>>(hChunk, resChunk, bc[l] + c0, dinv, colptr,
                                              csr_src, csr_w, nxtHi + c0, nxtLo + c0, Nf, CW);
        }
    }

    // ---- output projection: x4 (region A, 2048 wide) @ Wo[2048,1000] + bo -> d_out
    u16* oPanel    = (u16*)hRegion;                 // h region is free now
    u16* oPanel_lo = oPanel + (size_t)1024 * 2048;
    k_wpanel<<<dim3(2048 / 32, 1024 / 32), dim3(32, 8), 0, stream>>>(Wo, 1000, 0, 1000, 2048,
                                                                     oPanel, oPanel_lo);
    mgemm<true, true><<<dim3(1024 / 128, NN / 128), 256, 0, stream>>>(
        regA_hi, regA_lo, oPanel, oPanel_lo, bo, (float*)d_out, 2048, 1000, 1000);
}

// Round 4
// 2642.604 us; speedup vs baseline: 5.2035x; 1.6511x over previous
//
#include <hip/hip_runtime.h>
#include <math.h>

// GCN forward: 4 × [res = x@Wr+br ; x = relu(GCNConv(x) + res)] ; out = x@Wo+bo
// Round 4: split-bf16 MFMA GEMM upgraded:
//  - 2-phase pipeline (LDS double-buffer, stage t+1 before compute t, one barrier/step)
//  - concat [Wr|Wc] single GEMM per 512-col chunk (halves A traffic)
//  - XCD-aware block swizzle (grid 512 = 64/XCD, contiguous A-panels per XCD)
//  - L4 (K=4096) as two K=2048 passes with fp32 accumulate in C
// Memory: ws ~219 MB (planes 201.3 + h 16.8 + CSR ~1); d_out holds res (16.8) + panel (8.4).

#define NN 8192
#define NE 65536
#define CW 512            // columns per weight per chunk (concat GEMM is 2*CW wide)

typedef float f32x4 __attribute__((ext_vector_type(4)));
typedef __bf16 bf16x8 __attribute__((ext_vector_type(8)));
typedef unsigned short u16;

__device__ __forceinline__ u16 f2bf(float f) {          // RNE fp32 -> bf16 bits
    unsigned int u = __float_as_uint(f);
    u += 0x7FFFu + ((u >> 16) & 1u);
    return (u16)(u >> 16);
}
__device__ __forceinline__ float bf2f(u16 h) {
    return __uint_as_float(((unsigned int)h) << 16);
}

// ---------------------------------------------------------------- CSR kernels
__global__ void k_init_deg(float* __restrict__ deg) {
    int i = blockIdx.x * 256 + threadIdx.x;
    if (i < NN) deg[i] = 1.0f;
}
__global__ void k_zero_cnt(int* __restrict__ cnt) {
    int i = blockIdx.x * 256 + threadIdx.x;
    if (i < NN) cnt[i] = 0;
}
__global__ void k_deg_edges(const int* __restrict__ col, const float* __restrict__ ew,
                            float* __restrict__ deg) {
    int e = blockIdx.x * 256 + threadIdx.x;
    if (e < NE) atomicAdd(&deg[col[e]], ew[e]);
}
__global__ void k_cnt_edges(const int* __restrict__ col, int* __restrict__ cnt) {
    int e = blockIdx.x * 256 + threadIdx.x;
    if (e < NE) atomicAdd(&cnt[col[e]], 1);
}
__global__ void k_dinv(const float* __restrict__ deg, float* __restrict__ dinv) {
    int i = blockIdx.x * 256 + threadIdx.x;
    if (i < NN) { float d = deg[i]; dinv[i] = d > 0.f ? rsqrtf(d) : 0.f; }
}
__global__ __launch_bounds__(1024) void k_scan(const int* __restrict__ cnt,
                                               int* __restrict__ colptr,
                                               int* __restrict__ fillpos) {
    __shared__ int part[1024];
    int tid = threadIdx.x;
    int local[8];
    int s = 0;
#pragma unroll
    for (int i = 0; i < 8; ++i) { local[i] = cnt[tid * 8 + i]; s += local[i]; }
    part[tid] = s;
    __syncthreads();
    for (int off = 1; off < 1024; off <<= 1) {
        int add = (tid >= off) ? part[tid - off] : 0;
        __syncthreads();
        part[tid] += add;
        __syncthreads();
    }
    int run = (tid == 0) ? 0 : part[tid - 1];
#pragma unroll
    for (int i = 0; i < 8; ++i) {
        colptr[tid * 8 + i] = run;
        fillpos[tid * 8 + i] = run;
        run += local[i];
    }
    if (tid == 1023) colptr[NN] = run;
}
__global__ void k_fill(const int* __restrict__ row, const int* __restrict__ col,
                       const float* __restrict__ ew, const float* __restrict__ dinv,
                       int* __restrict__ fillpos, int* __restrict__ csr_src,
                       float* __restrict__ csr_w) {
    int e = blockIdx.x * 256 + threadIdx.x;
    if (e >= NE) return;
    int r = row[e], c = col[e];
    float nrm = dinv[r] * ew[e] * dinv[c];
    int p = atomicAdd(&fillpos[c], 1);
    csr_src[p] = r;
    csr_w[p] = nrm;
}

// ------------------------------------------------------------- split fp32->hi/lo
__global__ void k_split_x(const float* __restrict__ x, u16* __restrict__ hi,
                          u16* __restrict__ lo, int n) {
    int i = blockIdx.x * 256 + threadIdx.x;
    if (i >= n) return;
    float v = x[i];
    u16 h = f2bf(v);
    hi[i] = h;
    lo[i] = f2bf(v - bf2f(h));
}

// --------------------------------------- weight panel: transpose + split (concat)
// Panel rows n in [0,1024): n<half -> W0 col (c0+n), else W1 col (c0+n-half).
// k global = koff + local k; panel [1024][Kpass] K-contiguous hi/lo.
__global__ __launch_bounds__(256) void k_wpanel(const float* __restrict__ W0,
                                                const float* __restrict__ W1,
                                                int ldw, int nvalid, int c0, int half,
                                                int Kpass, int koff,
                                                u16* __restrict__ phi,
                                                u16* __restrict__ plo) {
    __shared__ float t[32][33];
    const int k0 = blockIdx.x * 32;
    const int n0 = blockIdx.y * 32;
    const int tx = threadIdx.x, ty = threadIdx.y;     // (32, 8)
#pragma unroll
    for (int i = 0; i < 4; ++i) {
        int k = koff + k0 + ty + i * 8;
        int n = n0 + tx;
        int cidx = (n < half) ? (c0 + n) : (c0 + n - half);
        const float* W = (n < half) ? W0 : W1;
        t[ty + i * 8][tx] = (cidx < nvalid) ? W[(size_t)k * ldw + cidx] : 0.f;
    }
    __syncthreads();
#pragma unroll
    for (int i = 0; i < 4; ++i) {
        int n = n0 + ty + i * 8;          // panel row
        int k = k0 + tx;
        float v = t[tx][ty + i * 8];
        u16 h = f2bf(v);
        phi[(size_t)n * Kpass + k] = h;
        plo[(size_t)n * Kpass + k] = f2bf(v - bf2f(h));
    }
}

// ---------------------------------------------------- split-bf16 MFMA GEMM, 2-phase
// C[8192 x 1024] = A[8192 x Kpass] @ panel^T (+bias). 128x128 tile, BK=32,
// 4 waves (2x2), wave 64x64 (4x4 frags 16x16), triple MFMA (hi*hi+lo*hi+hi*lo).
// Grid fixed (8,64) with XCD swizzle. LDS: 2 bufs x 4 tiles x 8KB = 64KB.
#define GLDS(g, l) __builtin_amdgcn_global_load_lds(                         \
    (const __attribute__((address_space(1))) void*)(g),                      \
    (__attribute__((address_space(3))) void*)(l), 16, 0, 0)

template <bool SPLITC, bool GUARD, bool ACCUM, bool BIAS>
__global__ __launch_bounds__(256) void mgemm(const u16* __restrict__ Ahi,
                                             const u16* __restrict__ Alo, int Astr,
                                             const u16* __restrict__ Bhi,
                                             const u16* __restrict__ Blo,
                                             const float* __restrict__ bias,
                                             float* __restrict__ Cres,
                                             float* __restrict__ Ch,
                                             int ldc, int Kpass, int Nvalid) {
    __shared__ __align__(16) u16 smem[32768];          // 64KB: 2 bufs x 32KB
    char* sm = (char*)smem;
    const int tid  = threadIdx.x;
    const int lane = tid & 63;
    const int w    = tid >> 6;
    const int wr   = w >> 1, wc = w & 1;

    // XCD swizzle: grid is (8,64); give each XCD 64 contiguous tiles (8 A-panels)
    const int orig = blockIdx.y * 8 + blockIdx.x;
    const int swz  = (orig & 7) * 64 + (orig >> 3);
    const int row0 = (swz >> 3) * 128;
    const int col0 = (swz & 7) * 128;

    // staging: pass p covers LDS linear [(p*4+w)*1024, +1024) bytes per tile
    size_t aoffg[2], boffg[2];
    unsigned ldsoff[2];
#pragma unroll
    for (int p = 0; p < 2; ++p) {
        int idx = ((p * 4 + w) << 6) + lane;          // 0..511 (16B units)
        int r = idx >> 2;
        int s = (idx & 3) ^ ((r >> 1) & 3);           // inverse swizzle on source
        aoffg[p] = (size_t)(row0 + r) * Astr + s * 8;
        boffg[p] = (size_t)(col0 + r) * Kpass + s * 8;
        ldsoff[p] = (unsigned)((p * 4 + w) << 10);
    }

    // fragment LDS byte offsets (row*64 + swizzled 16B slot), within one 8KB tile
    const int swzr = (((lane >> 4) ^ ((lane >> 1) & 3)) << 4);
    int aoff[4], boff[4];
#pragma unroll
    for (int m = 0; m < 4; ++m) {
        aoff[m] = (wr * 64 + m * 16 + (lane & 15)) * 64 + swzr;
        boff[m] = (wc * 64 + m * 16 + (lane & 15)) * 64 + swzr;
    }

    f32x4 acc[4][4];
#pragma unroll
    for (int m = 0; m < 4; ++m)
#pragma unroll
        for (int n = 0; n < 4; ++n) acc[m][n] = (f32x4){0.f, 0.f, 0.f, 0.f};

    const int NT = Kpass >> 5;

#define STAGE(buf, kk)                                                        \
    {                                                                         \
        char* bb = sm + (buf) * 32768;                                        \
        _Pragma("unroll")                                                     \
        for (int p = 0; p < 2; ++p) {                                         \
            GLDS(Ahi + aoffg[p] + (kk), bb + 0     + ldsoff[p]);              \
            GLDS(Alo + aoffg[p] + (kk), bb + 8192  + ldsoff[p]);              \
            GLDS(Bhi + boffg[p] + (kk), bb + 16384 + ldsoff[p]);              \
            GLDS(Blo + boffg[p] + (kk), bb + 24576 + ldsoff[p]);              \
        }                                                                     \
    }

    STAGE(0, 0);
    __syncthreads();

    int cur = 0;
    for (int t = 0; t < NT; ++t) {
        if (t + 1 < NT) STAGE(cur ^ 1, (t + 1) * 32);
        char* bb = sm + cur * 32768;
        bf16x8 ah[4], al[4], bh[4], bl[4];
#pragma unroll
        for (int m = 0; m < 4; ++m) {
            ah[m] = *(const bf16x8*)(bb + 0     + aoff[m]);
            al[m] = *(const bf16x8*)(bb + 8192  + aoff[m]);
            bh[m] = *(const bf16x8*)(bb + 16384 + boff[m]);
            bl[m] = *(const bf16x8*)(bb + 24576 + boff[m]);
        }
        __builtin_amdgcn_s_setprio(1);
#pragma unroll
        for (int m = 0; m < 4; ++m)
#pragma unroll
            for (int n = 0; n < 4; ++n) {
                acc[m][n] = __builtin_amdgcn_mfma_f32_16x16x32_bf16(ah[m], bh[n], acc[m][n], 0, 0, 0);
                acc[m][n] = __builtin_amdgcn_mfma_f32_16x16x32_bf16(al[m], bh[n], acc[m][n], 0, 0, 0);
                acc[m][n] = __builtin_amdgcn_mfma_f32_16x16x32_bf16(ah[m], bl[n], acc[m][n], 0, 0, 0);
            }
        __builtin_amdgcn_s_setprio(0);
        __syncthreads();
        cur ^= 1;
    }
#undef STAGE

    // epilogue: C/D layout col = lane&15, row = (lane>>4)*4 + j  [verified]
#pragma unroll
    for (int m = 0; m < 4; ++m) {
        const int r = row0 + wr * 64 + m * 16 + ((lane >> 4) << 2);
#pragma unroll
        for (int n = 0; n < 4; ++n) {
            const int cl = col0 + wc * 64 + n * 16 + (lane & 15);
            if (GUARD && cl >= Nvalid) continue;
            float* dst;
            float b = 0.f;
            if (SPLITC) {
                const bool isRes = cl < ldc;
                dst = isRes ? (Cres + (size_t)r * ldc + cl)
                            : (Ch + (size_t)r * ldc + (cl - ldc));
                if (BIAS && isRes) b = bias[cl];
            } else {
                dst = Cres + (size_t)r * ldc + cl;
                if (BIAS) b = bias[cl];
            }
#pragma unroll
            for (int j = 0; j < 4; ++j) {
                float v = acc[m][n][j] + b;
                if (ACCUM) v += dst[(size_t)j * ldc];
                dst[(size_t)j * ldc] = v;
            }
        }
    }
}

// ------------------------- fused aggregate + bias + residual + relu + split-write
__global__ __launch_bounds__(128) void k_fuse(const float* __restrict__ h,
                                              const float* __restrict__ res,
                                              const float* __restrict__ bcp,
                                              const float* __restrict__ dinv,
                                              const int* __restrict__ colptr,
                                              const int* __restrict__ csr_src,
                                              const float* __restrict__ csr_w,
                                              u16* __restrict__ ohi,
                                              u16* __restrict__ olo, int ldout) {
    const int node = blockIdx.x;
    const int f = threadIdx.x << 2;                     // 0..508
    const float di = dinv[node];
    const float sn = di * di;
    const float4 hv = *(const float4*)(h + (size_t)node * CW + f);
    float4 s = make_float4(sn * hv.x, sn * hv.y, sn * hv.z, sn * hv.w);
    const int e1 = colptr[node + 1];
    for (int e = colptr[node]; e < e1; ++e) {
        const int src = csr_src[e];
        const float wgt = csr_w[e];
        const float4 v = *(const float4*)(h + (size_t)src * CW + f);
        s.x = fmaf(wgt, v.x, s.x);
        s.y = fmaf(wgt, v.y, s.y);
        s.z = fmaf(wgt, v.z, s.z);
        s.w = fmaf(wgt, v.w, s.w);
    }
    const float4 r = *(const float4*)(res + (size_t)node * CW + f);
    const float4 b = *(const float4*)(bcp + f);
    float o0 = fmaxf(s.x + b.x + r.x, 0.f);
    float o1 = fmaxf(s.y + b.y + r.y, 0.f);
    float o2 = fmaxf(s.z + b.z + r.z, 0.f);
    float o3 = fmaxf(s.w + b.w + r.w, 0.f);
    ushort4 vh, vl;
    vh.x = f2bf(o0); vl.x = f2bf(o0 - bf2f(vh.x));
    vh.y = f2bf(o1); vl.y = f2bf(o1 - bf2f(vh.y));
    vh.z = f2bf(o2); vl.z = f2bf(o2 - bf2f(vh.z));
    vh.w = f2bf(o3); vl.w = f2bf(o3 - bf2f(vh.w));
    const size_t oidx = (size_t)node * ldout + f;
    *(ushort4*)(ohi + oidx) = vh;
    *(ushort4*)(olo + oidx) = vl;
}

// ---------------------------------------------------------------- launch
extern "C" void kernel_launch(void* const* d_in, const int* in_sizes, int n_in,
                              void* d_out, int out_size, void* d_ws, size_t ws_size,
                              hipStream_t stream) {
    const float* x  = (const float*)d_in[0];
    const int*   ei = (const int*)d_in[1];
    const float* ew = (const float*)d_in[2];
    const int* row = ei;
    const int* col = ei + NE;
    const float *Wc[4], *bc[4], *Wr[4], *br[4];
    for (int i = 0; i < 4; ++i) {
        Wc[i] = (const float*)d_in[3 + 4 * i];
        bc[i] = (const float*)d_in[4 + 4 * i];
        Wr[i] = (const float*)d_in[5 + 4 * i];
        br[i] = (const float*)d_in[6 + 4 * i];
    }
    const float* Wo = (const float*)d_in[19];
    const float* bo = (const float*)d_in[20];

    // ---- ws arena (~219 MB): regA (2048-wide hi/lo) | regB (4096-wide hi/lo) | h | CSR
    char* wsb = (char*)d_ws;
    u16* regA_hi = (u16*)wsb;                                   // 33.55 MB
    u16* regA_lo = regA_hi + (size_t)NN * 2048;                 // 33.55 MB
    u16* regB_hi = regA_lo + (size_t)NN * 2048;                 // 67.1 MB
    u16* regB_lo = regB_hi + (size_t)NN * 4096;                 // 67.1 MB
    float* hbuf  = (float*)(regB_lo + (size_t)NN * 4096);       // 16.78 MB
    float* deg   = hbuf + (size_t)NN * CW;
    float* dinv  = deg + NN;
    float* csr_w = dinv + NN;
    int* cnt     = (int*)(csr_w + NE);
    int* fillpos = cnt + NN;
    int* colptr  = fillpos + NN;
    int* csr_src = colptr + NN + 8;

    // d_out scratch: res chunk [0, 16.78MB) + weight panel [16.78MB, +8.39MB)
    float* resbuf = (float*)d_out;
    u16* panel    = (u16*)((float*)d_out + (size_t)NN * CW);
    // panel_lo at panel + 1024*Kpass (set per layer)

    // ---- preprocessing
    k_init_deg<<<NN / 256, 256, 0, stream>>>(deg);
    k_zero_cnt<<<NN / 256, 256, 0, stream>>>(cnt);
    k_deg_edges<<<NE / 256, 256, 0, stream>>>(col, ew, deg);
    k_cnt_edges<<<NE / 256, 256, 0, stream>>>(col, cnt);
    k_dinv<<<NN / 256, 256, 0, stream>>>(deg, dinv);
    k_scan<<<1, 1024, 0, stream>>>(cnt, colptr, fillpos);
    k_fill<<<NE / 256, 256, 0, stream>>>(row, col, ew, dinv, fillpos, csr_src, csr_w);

    // ---- split input x0 -> regA (512-wide)
    k_split_x<<<(NN * 512) / 256, 256, 0, stream>>>(x, regA_hi, regA_lo, NN * 512);

    // ---- 4 GCN layers
    const int dims[5] = {512, 1024, 2048, 4096, 2048};
    const dim3 ggrid(8, 64);
    for (int l = 0; l < 4; ++l) {
        const int K = dims[l], Nf = dims[l + 1];
        const int passes = (K > 2048) ? 2 : 1;
        const int Kpass = K / passes;
        const u16 *curHi, *curLo;
        u16 *nxtHi, *nxtLo;
        if ((l & 1) == 0) { curHi = regA_hi; curLo = regA_lo; nxtHi = regB_hi; nxtLo = regB_lo; }
        else              { curHi = regB_hi; curLo = regB_lo; nxtHi = regA_hi; nxtLo = regA_lo; }
        u16* plo = panel + (size_t)1024 * Kpass;
        const dim3 wgrid(Kpass / 32, 32);
        for (int c0 = 0; c0 < Nf; c0 += CW) {
            // pass 0
            k_wpanel<<<wgrid, dim3(32, 8), 0, stream>>>(Wr[l], Wc[l], Nf, Nf, c0, CW,
                                                        Kpass, 0, panel, plo);
            mgemm<true, false, false, true><<<ggrid, 256, 0, stream>>>(
                curHi, curLo, K, panel, plo, br[l] + c0, resbuf, hbuf, CW, Kpass, 1024);
            if (passes == 2) {
                k_wpanel<<<wgrid, dim3(32, 8), 0, stream>>>(Wr[l], Wc[l], Nf, Nf, c0, CW,
                                                            Kpass, Kpass, panel, plo);
                mgemm<true, false, true, false><<<ggrid, 256, 0, stream>>>(
                    curHi + Kpass, curLo + Kpass, K, panel, plo, nullptr, resbuf, hbuf,
                    CW, Kpass, 1024);
            }
            k_fuse<<<NN, 128, 0, stream>>>(hbuf, resbuf, bc[l] + c0, dinv, colptr,
                                           csr_src, csr_w, nxtHi + c0, nxtLo + c0, Nf);
        }
    }

    // ---- output projection: x4 (regA, 2048-wide) @ Wo[2048,1000] + bo -> d_out
    // panel for Wo lives in hbuf region (free now); 1024 padded cols x 2048 K
    u16* opanel    = (u16*)hbuf;
    u16* opanel_lo = opanel + (size_t)1024 * 2048;
    k_wpanel<<<dim3(2048 / 32, 32), dim3(32, 8), 0, stream>>>(Wo, Wo, 1000, 1000, 0, 1024,
                                                              2048, 0, opanel, opanel_lo);
    mgemm<false, true, false, true><<<ggrid, 256, 0, stream>>>(
        regA_hi, regA_lo, 2048, opanel, opanel_lo, bo, (float*)d_out, nullptr,
        1000, 2048, 1000);
}